// Round 2
// baseline (376.823 us; speedup 1.0000x reference)
//
#include <hip/hip_runtime.h>

// NCC loss, fused z-sweep, v2:
//  - sliding-window x-filter (192 thr x 4 outputs, re-read subtraction)
//  - sliding-window y-filter (128 thr x 4 outputs) + redistribute via yf buffer
//  - register prefetch of next slice (async-stage split), 2 barriers/slice
// Tile 32(x) x 16(y), z-chunk 20, halo 4 (KS=9). Grid 800 x 512.

#define TX 32
#define TY 16
#define ZC 20
#define PH 24          // plane height  = TY+8
#define PW 40          // plane width   = TX+8
#define PWP 41         // padded stride (float2)
#define XFP 33         // xf padded stride (float4 / float)
#define NSTEP 28       // ZC+8
#define NN 160
#define NPLANE (160*160)

__global__ void ncc_zero_ws(float* ws) { ws[0] = 0.0f; }

__global__ __launch_bounds__(512, 6)
void ncc_fused(const float* __restrict__ pred, const float* __restrict__ target,
               float* __restrict__ ws) {
  __shared__ float2 st[PH * PWP];        // staged (t,p) plane      7.9 KB
  __shared__ float4 xfa[PH * XFP];       // x-filt (t,p,t2,p2)     12.7 KB
  __shared__ float  xfb[PH * XFP];       // x-filt tp               3.2 KB
  __shared__ float4 yfa[TY * TX];        // xy-filt (t,p,t2,p2)     8.2 KB
  __shared__ float  yfb[TY * TX];        // xy-filt tp              2.0 KB
  __shared__ float  wsum[8];

  const int tid = threadIdx.x;
  int b = blockIdx.x;
  const int xt = b % 5;  b /= 5;
  const int yt = b % 10; b /= 10;
  const int zc = b % 8;  b /= 8;
  const int x0 = xt * TX, y0 = yt * TY, z0 = zc * ZC;
  const size_t bbase = (size_t)b * (size_t)(NN * NPLANE);

  // ---- staging geometry (hoisted; 2 positions/thread) ----
  const int pos0 = tid;                       // < 960
  const int yy0 = pos0 / PW, xx0 = pos0 - yy0 * PW;
  const int gy0 = y0 + yy0 - 4, gx0 = x0 + xx0 - 4;
  const bool rv0 = ((unsigned)gy0 < NN) && ((unsigned)gx0 < NN);
  const int off0 = gy0 * NN + gx0;
  const int sa0 = yy0 * PWP + xx0;
  const int pos1 = tid + 512;
  const bool has1 = (pos1 < PH * PW);
  const int yy1 = pos1 / PW, xx1 = pos1 - yy1 * PW;
  const int gy1 = y0 + yy1 - 4, gx1 = x0 + xx1 - 4;
  const bool rv1 = has1 && ((unsigned)gy1 < NN) && ((unsigned)gx1 < NN);
  const int off1 = gy1 * NN + gx1;
  const int sa1 = yy1 * PWP + xx1;

  // ---- phase-role geometry (hoisted) ----
  const int xrow = tid >> 3;                  // xf: 0..23 (tid<192)
  const int xg   = tid & 7;                   // xf: 0..7
  const int xbase = xrow * PWP + xg * 4;
  const int xout  = xrow * XFP + xg * 4;
  const int yx  = tid & 31;                   // yf: 0..31 (tid<128)
  const int yg  = tid >> 5;                   // yf: 0..3
  const int tx  = tid & 31;                   // owner
  const int ty  = tid >> 5;                   // owner 0..15
  const int oaddr = ty * TX + tx;

  float rt0, rp0, rt1, rp1;                   // prefetch regs
  #define PREFETCH(SS) do {                                                    \
    const int zi_ = z0 - 4 + (SS);                                             \
    const bool zv_ = ((unsigned)zi_ < NN);                                     \
    const float* tb_ = target + bbase + (size_t)zi_ * NPLANE;                  \
    const float* pb_ = pred   + bbase + (size_t)zi_ * NPLANE;                  \
    rt0 = (zv_ && rv0) ? tb_[off0] : 0.0f;                                     \
    rp0 = (zv_ && rv0) ? pb_[off0] : 0.0f;                                     \
    rt1 = (zv_ && rv1) ? tb_[off1] : 0.0f;                                     \
    rp1 = (zv_ && rv1) ? pb_[off1] : 0.0f;                                     \
  } while (0)

  float buf0[9], buf1[9], buf2[9], buf3[9], buf4[9];
  float run0 = 0, run1 = 0, run2 = 0, run3 = 0, run4 = 0;
  #pragma unroll
  for (int j = 0; j < 9; ++j) { buf0[j]=0; buf1[j]=0; buf2[j]=0; buf3[j]=0; buf4[j]=0; }
  float acc = 0.0f;
  const float inv_kvol = 1.0f / 729.0f;

  // ---- prologue: stage slice 0, issue slice 1 ----
  PREFETCH(0);
  st[sa0] = make_float2(rt0, rp0);
  if (has1) st[sa1] = make_float2(rt1, rp1);
  PREFETCH(1);
  __syncthreads();

  for (int s0 = 0; s0 < NSTEP; s0 += 9) {
    #pragma unroll
    for (int pp = 0; pp < 9; ++pp) {
      const int s = s0 + pp;
      if (s < NSTEP) {
        // ---- phase 1: x-filter (sliding, 4 outputs/thread) ----
        if (tid < 192) {
          float s_t = 0, s_p = 0, s_t2 = 0, s_p2 = 0, s_tp = 0;
          #pragma unroll
          for (int k = 0; k < 9; ++k) {
            const float2 v = st[xbase + k];
            s_t += v.x; s_p += v.y;
            s_t2 = fmaf(v.x, v.x, s_t2);
            s_p2 = fmaf(v.y, v.y, s_p2);
            s_tp = fmaf(v.x, v.y, s_tp);
          }
          xfa[xout] = make_float4(s_t, s_p, s_t2, s_p2);
          xfb[xout] = s_tp;
          #pragma unroll
          for (int k = 0; k < 3; ++k) {
            const float2 vn = st[xbase + 9 + k];
            const float2 vo = st[xbase + k];
            s_t += vn.x - vo.x;
            s_p += vn.y - vo.y;
            s_t2 = fmaf(vn.x, vn.x, s_t2); s_t2 = fmaf(-vo.x, vo.x, s_t2);
            s_p2 = fmaf(vn.y, vn.y, s_p2); s_p2 = fmaf(-vo.y, vo.y, s_p2);
            s_tp = fmaf(vn.x, vn.y, s_tp); s_tp = fmaf(-vo.x, vo.y, s_tp);
            xfa[xout + 1 + k] = make_float4(s_t, s_p, s_t2, s_p2);
            xfb[xout + 1 + k] = s_tp;
          }
        }
        __syncthreads();   // barrier A: xf ready; st(s) reads done

        // ---- phase 2a: write next slice into st (regs prefetched last iter) ----
        st[sa0] = make_float2(rt0, rp0);
        if (has1) st[sa1] = make_float2(rt1, rp1);
        // ---- phase 2b: issue loads for slice s+2 ----
        if (s + 2 < NSTEP) { PREFETCH(s + 2); }
        // ---- phase 2c: y-filter (sliding, 4 outputs/thread) ----
        if (tid < 128) {
          float w_t = 0, w_p = 0, w_t2 = 0, w_p2 = 0, w_tp = 0;
          #pragma unroll
          for (int k = 0; k < 9; ++k) {
            const float4 a = xfa[(yg * 4 + k) * XFP + yx];
            const float  c = xfb[(yg * 4 + k) * XFP + yx];
            w_t += a.x; w_p += a.y; w_t2 += a.z; w_p2 += a.w; w_tp += c;
          }
          yfa[(yg * 4) * TX + yx] = make_float4(w_t, w_p, w_t2, w_p2);
          yfb[(yg * 4) * TX + yx] = w_tp;
          #pragma unroll
          for (int k = 0; k < 3; ++k) {
            const float4 an = xfa[(yg * 4 + 9 + k) * XFP + yx];
            const float  cn = xfb[(yg * 4 + 9 + k) * XFP + yx];
            const float4 ao = xfa[(yg * 4 + k) * XFP + yx];
            const float  co = xfb[(yg * 4 + k) * XFP + yx];
            w_t += an.x - ao.x; w_p += an.y - ao.y;
            w_t2 += an.z - ao.z; w_p2 += an.w - ao.w; w_tp += cn - co;
            yfa[(yg * 4 + 1 + k) * TX + yx] = make_float4(w_t, w_p, w_t2, w_p2);
            yfb[(yg * 4 + 1 + k) * TX + yx] = w_tp;
          }
        }
        __syncthreads();   // barrier B: yf + st(s+1) ready

        // ---- phase 3: owner — z ring + NCC ----
        {
          const float4 a = yfa[oaddr];
          const float  c = yfb[oaddr];
          run0 += a.x - buf0[pp]; buf0[pp] = a.x;
          run1 += a.y - buf1[pp]; buf1[pp] = a.y;
          run2 += a.z - buf2[pp]; buf2[pp] = a.z;
          run3 += a.w - buf3[pp]; buf3[pp] = a.w;
          run4 += c   - buf4[pp]; buf4[pp] = c;
          if (s >= 8) {
            const float tavg = run0 * inv_kvol;
            const float pavg = run1 * inv_kvol;
            const float cross = run4 - pavg * run0;
            const float tvar  = run2 - tavg * run0;
            const float pvar  = run3 - pavg * run1;
            acc += (cross * cross) / (tvar * pvar + 1e-5f);
          }
        }
      }
    }
  }

  // ---- reduction: wave shuffle -> LDS -> one atomicAdd per block ----
  __syncthreads();
  #pragma unroll
  for (int off = 32; off > 0; off >>= 1)
    acc += __shfl_down(acc, off, 64);
  if ((tid & 63) == 0) wsum[tid >> 6] = acc;
  __syncthreads();
  if (tid == 0) {
    float tot = 0.0f;
    #pragma unroll
    for (int w = 0; w < 8; ++w) tot += wsum[w];
    atomicAdd(ws, tot);
  }
}

__global__ void ncc_finalize(const float* __restrict__ ws, float* __restrict__ out) {
  out[0] = -ws[0] * (1.0f / 8192000.0f);
}

extern "C" void kernel_launch(void* const* d_in, const int* in_sizes, int n_in,
                              void* d_out, int out_size, void* d_ws, size_t ws_size,
                              hipStream_t stream) {
  const float* pred   = (const float*)d_in[0];
  const float* target = (const float*)d_in[1];
  float* out = (float*)d_out;
  float* ws  = (float*)d_ws;

  ncc_zero_ws<<<1, 1, 0, stream>>>(ws);
  ncc_fused<<<800, 512, 0, stream>>>(pred, target, ws);
  ncc_finalize<<<1, 1, 0, stream>>>(ws, out);
}

// Round 3
// 208.094 us; speedup vs baseline: 1.8108x; 1.8108x over previous
//
#include <hip/hip_runtime.h>

// NCC loss, fused z-sweep, v3 = R1 structure + one-slice-ahead register
// prefetch (T14 async-stage split). R1's exact LDS layouts (measured 0 bank
// conflicts). Tile 32(x) x 16(y), z-chunk 20, halo 4 (KS=9). Grid 800 x 512.
//
// Per slice: xf (9-tap x-filter from st) -> barrier A -> write st(s+1) from
// prefetch regs + issue loads for s+2 + yf (9-tap y-filter, per-thread
// column) + z-ring + NCC -> barrier B.

#define TX 32
#define TY 16
#define ZC 20
#define PH 24          // TY+8
#define PW 40          // TX+8
#define NSTEP 28       // ZC+8
#define NN 160
#define NPLANE (160*160)

__global__ void ncc_zero_ws(float* ws) { ws[0] = 0.0f; }

__global__ __launch_bounds__(512, 4)
void ncc_fused(const float* __restrict__ pred, const float* __restrict__ target,
               float* __restrict__ ws) {
  __shared__ float2 st[PH * PW];     // staged (t,p) plane   7.5 KB
  __shared__ float4 xf4[PH * TX];    // x-filt (t,p,t2,p2)  12.0 KB
  __shared__ float  xf1[PH * TX];    // x-filt tp            3.0 KB
  __shared__ float  wsum[8];

  const int tid = threadIdx.x;
  const int tx = tid & 31;
  const int ty = tid >> 5;           // 0..15

  int b = blockIdx.x;
  const int xt = b % 5;  b /= 5;
  const int yt = b % 10; b /= 10;
  const int zc = b % 8;  b /= 8;
  const int x0 = xt * TX, y0 = yt * TY, z0 = zc * ZC;
  const size_t bbase = (size_t)b * (size_t)NN * (size_t)NPLANE;

  // ---- staging geometry (hoisted; 2 positions/thread, 960 total) ----
  const int yy0 = tid / PW, xx0 = tid - yy0 * PW;
  const bool rv0 = ((unsigned)(y0 + yy0 - 4) < NN) && ((unsigned)(x0 + xx0 - 4) < NN);
  const int off0 = (y0 + yy0 - 4) * NN + (x0 + xx0 - 4);
  const int pos1 = tid + 512;
  const bool has1 = (pos1 < PH * PW);
  const int yy1 = pos1 / PW, xx1 = pos1 - yy1 * PW;
  const bool rv1 = has1 && ((unsigned)(y0 + yy1 - 4) < NN) && ((unsigned)(x0 + xx1 - 4) < NN);
  const int off1 = (y0 + yy1 - 4) * NN + (x0 + xx1 - 4);

  float rt0, rp0, rt1, rp1;          // prefetch regs (next slice)
#define PREFETCH(SS) do {                                                     \
    const int zi_ = z0 - 4 + (SS);                                            \
    const bool zv_ = ((unsigned)zi_ < NN);                                    \
    const size_t zb_ = bbase + (size_t)zi_ * (size_t)NPLANE;                  \
    rt0 = (zv_ && rv0) ? target[zb_ + off0] : 0.0f;                           \
    rp0 = (zv_ && rv0) ? pred[zb_ + off0]   : 0.0f;                           \
    rt1 = (zv_ && rv1) ? target[zb_ + off1] : 0.0f;                           \
    rp1 = (zv_ && rv1) ? pred[zb_ + off1]   : 0.0f;                           \
  } while (0)

  float buf0[9], buf1[9], buf2[9], buf3[9], buf4[9];
  float run0 = 0, run1 = 0, run2 = 0, run3 = 0, run4 = 0;
  #pragma unroll
  for (int j = 0; j < 9; ++j) { buf0[j]=0; buf1[j]=0; buf2[j]=0; buf3[j]=0; buf4[j]=0; }
  float acc = 0.0f;
  const float inv_kvol = 1.0f / 729.0f;

  // ---- prologue: stage slice 0, issue loads for slice 1 ----
  PREFETCH(0);
  st[tid] = make_float2(rt0, rp0);
  if (has1) st[pos1] = make_float2(rt1, rp1);
  PREFETCH(1);
  __syncthreads();

  for (int s0 = 0; s0 < NSTEP; s0 += 9) {
    #pragma unroll
    for (int pp = 0; pp < 9; ++pp) {
      const int s = s0 + pp;
      if (s < NSTEP) {
        // ---- phase 1: x-filter of slice s (in st) ----
        for (int pos = tid; pos < PH * TX; pos += 512) {
          const int yy = pos >> 5;
          const int xx = pos & 31;
          float s_t = 0, s_p = 0, s_t2 = 0, s_p2 = 0, s_tp = 0;
          #pragma unroll
          for (int dx = 0; dx < 9; ++dx) {
            const float2 v = st[yy * PW + xx + dx];
            s_t += v.x;
            s_p += v.y;
            s_t2 = fmaf(v.x, v.x, s_t2);
            s_p2 = fmaf(v.y, v.y, s_p2);
            s_tp = fmaf(v.x, v.y, s_tp);
          }
          xf4[pos] = make_float4(s_t, s_p, s_t2, s_p2);
          xf1[pos] = s_tp;
        }
        __syncthreads();   // A: xf done reading st; xf4/xf1 visible

        // ---- phase 2a: write slice s+1 into st (regs loaded last slice) ----
        st[tid] = make_float2(rt0, rp0);
        if (has1) st[pos1] = make_float2(rt1, rp1);
        // ---- phase 2b: issue loads for slice s+2 ----
        if (s + 2 < NSTEP) { PREFETCH(s + 2); }

        // ---- phase 2c: y-filter (per-thread column) ----
        float cur0 = 0, cur1 = 0, cur2 = 0, cur3 = 0, cur4 = 0;
        #pragma unroll
        for (int dy = 0; dy < 9; ++dy) {
          const float4 a = xf4[(ty + dy) * TX + tx];
          const float  c = xf1[(ty + dy) * TX + tx];
          cur0 += a.x; cur1 += a.y; cur2 += a.z; cur3 += a.w; cur4 += c;
        }

        // ---- phase 2d: z running window + NCC ----
        run0 += cur0 - buf0[pp]; buf0[pp] = cur0;
        run1 += cur1 - buf1[pp]; buf1[pp] = cur1;
        run2 += cur2 - buf2[pp]; buf2[pp] = cur2;
        run3 += cur3 - buf3[pp]; buf3[pp] = cur3;
        run4 += cur4 - buf4[pp]; buf4[pp] = cur4;
        if (s >= 8) {
          const float tavg = run0 * inv_kvol;
          const float pavg = run1 * inv_kvol;
          const float cross = run4 - pavg * run0;
          const float tvar  = run2 - tavg * run0;
          const float pvar  = run3 - pavg * run1;
          acc += (cross * cross) / (tvar * pvar + 1e-5f);
        }
        __syncthreads();   // B: yf reads of xf4/xf1 done; st(s+1) visible
      }
    }
  }

  // ---- reduction: wave shuffle -> LDS -> one atomicAdd per block ----
  #pragma unroll
  for (int off = 32; off > 0; off >>= 1)
    acc += __shfl_down(acc, off, 64);
  if ((tid & 63) == 0) wsum[tid >> 6] = acc;
  __syncthreads();
  if (tid == 0) {
    float tot = 0.0f;
    #pragma unroll
    for (int w = 0; w < 8; ++w) tot += wsum[w];
    atomicAdd(ws, tot);
  }
}

__global__ void ncc_finalize(const float* __restrict__ ws, float* __restrict__ out) {
  out[0] = -ws[0] * (1.0f / 8192000.0f);
}

extern "C" void kernel_launch(void* const* d_in, const int* in_sizes, int n_in,
                              void* d_out, int out_size, void* d_ws, size_t ws_size,
                              hipStream_t stream) {
  const float* pred   = (const float*)d_in[0];
  const float* target = (const float*)d_in[1];
  float* out = (float*)d_out;
  float* ws  = (float*)d_ws;

  ncc_zero_ws<<<1, 1, 0, stream>>>(ws);
  ncc_fused<<<800, 512, 0, stream>>>(pred, target, ws);
  ncc_finalize<<<1, 1, 0, stream>>>(ws, out);
}

// Round 4
// 174.965 us; speedup vs baseline: 2.1537x; 1.1893x over previous
//
#include <hip/hip_runtime.h>

// NCC loss, fused z-sweep, v4 = R1 math/layouts + double-buffered st & xf
// -> ONE barrier per slice. Stage(s+1) at top of body overlaps xf(s).
// Tile 32(x) x 16(y), z-chunk 20, halo 4 (KS=9). Grid 800 x 512.
//
// Hazard proof (single barrier): within iter s: stage->stB, xf: stA->xfA,
// SYNC, yf: xfA. Next iter stages stA (xf(s) finished reading it before the
// barrier all threads crossed), xf(s+1) reads stB (written pre-barrier,
// visible) and writes xfB (yf(s) reads xfA). Parity resolves all overlaps.

#define TX 32
#define TY 16
#define ZC 20
#define PH 24          // TY+8
#define PW 40          // TX+8
#define NSTEP 28       // ZC+8
#define NN 160
#define NPLANE (160*160)

__global__ void ncc_zero_ws(float* ws) { ws[0] = 0.0f; }

__global__ __launch_bounds__(512, 2)
void ncc_fused(const float* __restrict__ pred, const float* __restrict__ target,
               float* __restrict__ ws) {
  __shared__ float2 st[2][PH * PW];    // staged (t,p) planes   15.0 KB
  __shared__ float4 xf4[2][PH * TX];   // x-filt (t,p,t2,p2)    24.0 KB
  __shared__ float  xf1[2][PH * TX];   // x-filt tp              6.0 KB
  __shared__ float  wsum[8];

  const int tid = threadIdx.x;
  const int tx = tid & 31;
  const int ty = tid >> 5;             // 0..15

  int b = blockIdx.x;
  const int xt = b % 5;  b /= 5;
  const int yt = b % 10; b /= 10;
  const int zc = b % 8;  b /= 8;
  const int x0 = xt * TX, y0 = yt * TY, z0 = zc * ZC;
  const size_t bbase = (size_t)b * (size_t)NN * (size_t)NPLANE;

  float buf[5][9];
  float run0 = 0, run1 = 0, run2 = 0, run3 = 0, run4 = 0;
  #pragma unroll
  for (int f = 0; f < 5; ++f)
    #pragma unroll
    for (int j = 0; j < 9; ++j) buf[f][j] = 0.0f;
  float acc = 0.0f;
  const float inv_kvol = 1.0f / 729.0f;

  // ---- stage slice `SS` into buffer `DST` (zero-pad x,y,z) ----
#define STAGE(DST, SS) do {                                                   \
    const int zi_ = z0 - 4 + (SS);                                            \
    if ((unsigned)zi_ < NN) {                                                 \
      const size_t zb_ = bbase + (size_t)zi_ * (size_t)NPLANE;                \
      for (int pos = tid; pos < PH * PW; pos += 512) {                        \
        const int yy_ = pos / PW, xx_ = pos - yy_ * PW;                       \
        const int gy_ = y0 + yy_ - 4, gx_ = x0 + xx_ - 4;                     \
        float tv_ = 0.0f, pv_ = 0.0f;                                         \
        if ((unsigned)gy_ < NN && (unsigned)gx_ < NN) {                       \
          const size_t idx_ = zb_ + (size_t)(gy_ * NN + gx_);                 \
          tv_ = target[idx_]; pv_ = pred[idx_];                               \
        }                                                                     \
        (DST)[pos] = make_float2(tv_, pv_);                                   \
      }                                                                       \
    } else {                                                                  \
      for (int pos = tid; pos < PH * PW; pos += 512)                          \
        (DST)[pos] = make_float2(0.0f, 0.0f);                                 \
    }                                                                         \
  } while (0)

  // ---- prologue: stage slice 0 into buffer 0 ----
  STAGE(st[0], 0);
  __syncthreads();

  for (int s0 = 0; s0 < NSTEP; s0 += 9) {
    #pragma unroll
    for (int pp = 0; pp < 9; ++pp) {
      const int s = s0 + pp;
      if (s < NSTEP) {
        const int par = s & 1;
        const float2* stA = st[par];
        float4* xfa = xf4[par];
        float*  xfb = xf1[par];

        // ---- stage slice s+1 into the other buffer (overlaps xf) ----
        if (s + 1 < NSTEP) { STAGE(st[par ^ 1], s + 1); }

        // ---- x-filter of slice s ----
        for (int pos = tid; pos < PH * TX; pos += 512) {
          const int yy = pos >> 5;
          const int xx = pos & 31;
          float s_t = 0, s_p = 0, s_t2 = 0, s_p2 = 0, s_tp = 0;
          #pragma unroll
          for (int dx = 0; dx < 9; ++dx) {
            const float2 v = stA[yy * PW + xx + dx];
            s_t += v.x;
            s_p += v.y;
            s_t2 = fmaf(v.x, v.x, s_t2);
            s_p2 = fmaf(v.y, v.y, s_p2);
            s_tp = fmaf(v.x, v.y, s_tp);
          }
          xfa[pos] = make_float4(s_t, s_p, s_t2, s_p2);
          xfb[pos] = s_tp;
        }
        __syncthreads();   // xfA/stB visible; stA reads done

        // ---- y-filter (per-thread column) ----
        float cur0 = 0, cur1 = 0, cur2 = 0, cur3 = 0, cur4 = 0;
        #pragma unroll
        for (int dy = 0; dy < 9; ++dy) {
          const float4 a = xfa[(ty + dy) * TX + tx];
          const float  c = xfb[(ty + dy) * TX + tx];
          cur0 += a.x; cur1 += a.y; cur2 += a.z; cur3 += a.w; cur4 += c;
        }

        // ---- z running window + NCC (slot pp is compile-time static) ----
        run0 += cur0 - buf[0][pp]; buf[0][pp] = cur0;
        run1 += cur1 - buf[1][pp]; buf[1][pp] = cur1;
        run2 += cur2 - buf[2][pp]; buf[2][pp] = cur2;
        run3 += cur3 - buf[3][pp]; buf[3][pp] = cur3;
        run4 += cur4 - buf[4][pp]; buf[4][pp] = cur4;
        if (s >= 8) {
          const float tavg = run0 * inv_kvol;
          const float pavg = run1 * inv_kvol;
          const float cross = run4 - pavg * run0;
          const float tvar  = run2 - tavg * run0;
          const float pvar  = run3 - pavg * run1;
          acc += (cross * cross) / (tvar * pvar + 1e-5f);
        }
      }
    }
  }

  // ---- reduction: wave shuffle -> LDS -> one atomicAdd per block ----
  #pragma unroll
  for (int off = 32; off > 0; off >>= 1)
    acc += __shfl_down(acc, off, 64);
  if ((tid & 63) == 0) wsum[tid >> 6] = acc;
  __syncthreads();
  if (tid == 0) {
    float tot = 0.0f;
    #pragma unroll
    for (int w = 0; w < 8; ++w) tot += wsum[w];
    atomicAdd(ws, tot);
  }
}

__global__ void ncc_finalize(const float* __restrict__ ws, float* __restrict__ out) {
  out[0] = -ws[0] * (1.0f / 8192000.0f);
}

extern "C" void kernel_launch(void* const* d_in, const int* in_sizes, int n_in,
                              void* d_out, int out_size, void* d_ws, size_t ws_size,
                              hipStream_t stream) {
  const float* pred   = (const float*)d_in[0];
  const float* target = (const float*)d_in[1];
  float* out = (float*)d_out;
  float* ws  = (float*)d_ws;

  ncc_zero_ws<<<1, 1, 0, stream>>>(ws);
  ncc_fused<<<800, 512, 0, stream>>>(pred, target, ws);
  ncc_finalize<<<1, 1, 0, stream>>>(ws, out);
}